// Round 7
// baseline (584.907 us; speedup 1.0000x reference)
//
#include <hip/hip_runtime.h>

typedef unsigned short u16;
typedef unsigned int   u32;

#define NB     512
#define INC    256
#define NHEADS 8
#define HW     361
#define NPIX   184832      /* NB*HW */
#define NTOT   768
#define EPSBN  1e-5f

typedef __bf16 bf16x8 __attribute__((ext_vector_type(8)));
typedef float  f32x4  __attribute__((ext_vector_type(4)));

__device__ __forceinline__ u16 f2bf(float f) {
  u32 u = __float_as_uint(f);
  u += 0x7fffu + ((u >> 16) & 1u);          // round-to-nearest-even
  return (u16)(u >> 16);
}
__device__ __forceinline__ float bf2f(u16 v) {
  return __uint_as_float(((u32)v) << 16);
}

// ---------------- kernel 0: W -> bf16 [768][256] plain rows, bias, zero stats
__global__ __launch_bounds__(256) void k_prep(
    const float* __restrict__ Wq, const float* __restrict__ bq,
    const float* __restrict__ Wk, const float* __restrict__ bk,
    const float* __restrict__ Wv, const float* __restrict__ bv,
    u16* __restrict__ Wall, float* __restrict__ ball, float* __restrict__ stats) {
  const int n = blockIdx.x, t = threadIdx.x;
  const float* src; const float* bs; int r;
  if (n < 256)      { src = Wq; bs = bq; r = n; }
  else if (n < 512) { src = Wk; bs = bk; r = n - 256; }
  else              { src = Wv; bs = bv; r = n - 512; }
  Wall[n * 256 + t] = f2bf(src[r * 256 + t]);
  if (t == 0) ball[n] = bs[r];
  if (n == 0) { for (int i = t; i < 1536; i += 256) stats[i] = 0.f; }
}

// ---------------- kernel 0b: x [B][256][361] f32 -> xT [NPIX][256] bf16, ROTATED columns
// logical 16B granule g stored at physical slot (g + 4*(m&7)) & 31
__global__ __launch_bounds__(384) void k_xt(const float* __restrict__ x, u16* __restrict__ xT) {
  const int bb = blockIdx.x, t = threadIdx.x;
  if (t >= HW) return;
  const size_t m = (size_t)bb * HW + t;
  const float* xp = x + (size_t)bb * INC * HW + t;
  char* dst = (char*)xT + m * 512;
  const int rot = ((int)m & 7) * 4;
  #pragma unroll 1
  for (int cc = 0; cc < INC; cc += 32) {
    __align__(16) u16 tmp[32];
    #pragma unroll
    for (int c = 0; c < 32; ++c) tmp[c] = f2bf(xp[(size_t)(cc + c) * HW]);
    #pragma unroll
    for (int p = 0; p < 4; ++p) {
      int slot = ((cc >> 3) + p + rot) & 31;
      *(uint4*)(dst + slot * 16) = ((const uint4*)tmp)[p];
    }
  }
}

// ---------------- kernel 1: QKV GEMM, M-tile 64, 256 threads (4 waves),
// wave w covers heads {w, w+4} sequentially; outputs [bh][px][32c]
__global__ __launch_bounds__(256) void k_gemm(
    const u16* __restrict__ xT, const u16* __restrict__ Wall,
    const float* __restrict__ ball,
    u16* __restrict__ qQ, u16* __restrict__ qK, u16* __restrict__ qV,
    float* __restrict__ stats) {
  __shared__ u16   Al[64 * 256];                   // 32 KB, rotated rows
  __shared__ float bl[NTOT];
  const int tid = threadIdx.x;
  const int tx  = blockIdx.x;                      // 0..5 tile-in-image
  const int bb  = blockIdx.y;
  const int px0 = tx * 64;
  const int nvalid = (px0 + 64 <= HW) ? 64 : (HW - px0);   // 64 or 41
  {
    uint4* dst = (uint4*)Al;
    const uint4* src = (const uint4*)(xT + ((size_t)bb * HW + px0) * 256);
    #pragma unroll
    for (int i = 0; i < 8; ++i) {
      int idx = tid + i * 256;                     // 0..2047, 32 uint4 per row
      int row = idx >> 5;
      dst[idx] = (row < nvalid) ? src[idx] : make_uint4(0u, 0u, 0u, 0u);
    }
  }
  for (int i = tid; i < NTOT; i += 256) bl[i] = ball[i];
  __syncthreads();

  const int lane = tid & 63, w = tid >> 6;         // 4 waves
  const int l15 = lane & 15, kq = lane >> 4;
  // xT rotation: m&7 = (bb + row)&7, row ≡ l15 (mod 8)
  const int col0 = ((kq * 16) + (((l15 + bb) & 7) * 64)) & 511;
  const char* Alb = (const char*)Al;

  #pragma unroll 1
  for (int nt = 0; nt < 3; ++nt) {
    u16* qp = (nt == 0) ? qQ : (nt == 1) ? qK : qV;
    #pragma unroll 1
    for (int hh = 0; hh < 2; ++hh) {
      const int head = w + hh * 4;                 // 0..7
      f32x4 acc[4][2];
      #pragma unroll
      for (int i = 0; i < 4; ++i) {
        acc[i][0] = (f32x4){0.f,0.f,0.f,0.f};
        acc[i][1] = (f32x4){0.f,0.f,0.f,0.f};
      }

      const char* wrow0 = (const char*)Wall + (size_t)(nt * 256 + head * 32 + l15) * 512 + kq * 16;
      const char* wrow1 = wrow0 + 16 * 512;

      int col = col0;
      #pragma unroll
      for (int ks = 0; ks < 8; ++ks) {
        bf16x8 b0 = __builtin_bit_cast(bf16x8, *(const uint4*)(wrow0 + ks * 64));
        bf16x8 b1 = __builtin_bit_cast(bf16x8, *(const uint4*)(wrow1 + ks * 64));
        bf16x8 a[4];
        #pragma unroll
        for (int mi = 0; mi < 4; ++mi)
          a[mi] = __builtin_bit_cast(bf16x8, *(const uint4*)(Alb + (mi * 16 + l15) * 512 + col));
        col = (col + 64) & 511;
        #pragma unroll
        for (int mi = 0; mi < 4; ++mi) {
          acc[mi][0] = __builtin_amdgcn_mfma_f32_16x16x32_bf16(a[mi], b0, acc[mi][0], 0, 0, 0);
          acc[mi][1] = __builtin_amdgcn_mfma_f32_16x16x32_bf16(a[mi], b1, acc[mi][1], 0, 0, 0);
        }
      }

      const size_t obh = ((size_t)bb * NHEADS + head) * (32 * HW);
      #pragma unroll
      for (int ni = 0; ni < 2; ++ni) {
        const int c = ni * 16 + l15;               // 0..31 within head
        const int n = nt * 256 + head * 32 + c;
        const float bias = bl[n];
        float s = 0.f, q = 0.f;
        #pragma unroll
        for (int mi = 0; mi < 4; ++mi) {
          #pragma unroll
          for (int j = 0; j < 4; ++j) {
            const int pxr = mi * 16 + kq * 4 + j;  // row in tile
            if (pxr < nvalid) {
              float v = acc[mi][ni][j] + bias;
              qp[obh + (size_t)(px0 + pxr) * 32 + c] = f2bf(v);
              s += v; q += v * v;
            }
          }
        }
        s += __shfl_down(s, 32);  q += __shfl_down(q, 32);
        s += __shfl_down(s, 16);  q += __shfl_down(q, 16);
        if (kq == 0) {
          atomicAdd(&stats[n], s);
          atomicAdd(&stats[NTOT + n], q);
        }
      }
    }
  }
}

// ---------------- kernel 2: finalize BN -> s_all, t_all
__global__ void k_stats(const float* __restrict__ stats,
                        const float* __restrict__ gQ, const float* __restrict__ betaQ,
                        const float* __restrict__ gK, const float* __restrict__ betaK,
                        const float* __restrict__ gV, const float* __restrict__ betaV,
                        float* __restrict__ s_all, float* __restrict__ t_all) {
  const int n = threadIdx.x;
  if (n >= NTOT) return;
  const float invP = 1.f / (float)NPIX;
  float mean = stats[n] * invP;
  float var  = stats[NTOT + n] * invP - mean * mean;
  float g, be;
  if (n < 256)      { g = gQ[n];       be = betaQ[n]; }
  else if (n < 512) { g = gK[n - 256]; be = betaK[n - 256]; }
  else              { g = gV[n - 512]; be = betaV[n - 512]; }
  float s = g * rsqrtf(var + EPSBN);
  s_all[n] = s;
  t_all[n] = be - s * mean;
}

// ---------------- kernel 3: neighbor attention + softmax + ReLU + residual
// one block per (bb,h); K then V phase-share one 23KB LDS buffer (transposed on stage)
__global__ __launch_bounds__(384, 6) void k_attn(
    const u16* __restrict__ qQ, const u16* __restrict__ qK, const u16* __restrict__ qV,
    const float* __restrict__ s_all, const float* __restrict__ t_all,
    const float* __restrict__ x, float* __restrict__ out) {
  __shared__ __align__(16) u16 KV[32 * HW];          // [c][px]
  __shared__ float sQ[32], tQ[32], sK[32], tK[32], sV[32], tV[32];
  const int bb = blockIdx.x, h = blockIdx.y, tid = threadIdx.x;
  const int bh = bb * NHEADS + h;

  if (tid < 96) {
    int which = tid >> 5, c = tid & 31;
    float sv = s_all[which * 256 + h * 32 + c];
    float tv = t_all[which * 256 + h * 32 + c];
    if (which == 0)      { sQ[c] = sv; tQ[c] = tv; }
    else if (which == 1) { sK[c] = sv; tK[c] = tv; }
    else                 { sV[c] = sv; tV[c] = tv; }
  }
  // stage K: contiguous read [px][c], transpose into LDS [c][px]
  {
    const uint4* gk = (const uint4*)(qK + (size_t)bh * 11552);
    for (int i = tid; i < 1444; i += 384) {
      uint4 kk = gk[i];
      int px = i >> 2, c0 = (i & 3) << 3;
      u16* d = KV + c0 * HW + px;
      d[0 * HW] = (u16)(kk.x & 0xffffu); d[1 * HW] = (u16)(kk.x >> 16);
      d[2 * HW] = (u16)(kk.y & 0xffffu); d[3 * HW] = (u16)(kk.y >> 16);
      d[4 * HW] = (u16)(kk.z & 0xffffu); d[5 * HW] = (u16)(kk.z >> 16);
      d[6 * HW] = (u16)(kk.w & 0xffffu); d[7 * HW] = (u16)(kk.w >> 16);
    }
  }
  __syncthreads();

  const int px = tid;
  const bool act = tid < HW;
  float a0 = 0.f, a1 = 0.f, a2 = 0.f, a3 = 0.f;
  int pn0 = 0, pn1 = 0, pn2 = 0, pn3 = 0;
  if (act) {
    const int yy = px / 19, xx = px - yy * 19;
    const bool i0 = yy > 0, i1 = yy < 18, i2 = xx > 0, i3 = xx < 18;
    pn0 = i0 ? px - 19 : px;  pn1 = i1 ? px + 19 : px;
    pn2 = i2 ? px - 1  : px;  pn3 = i3 ? px + 1  : px;
    const u16* K0 = KV + pn0; const u16* K1 = KV + pn1;
    const u16* K2 = KV + pn2; const u16* K3 = KV + pn3;
    const uint4* q4 = (const uint4*)(qQ + ((size_t)bh * HW + px) * 32);
    uint4 qA = q4[0], qB = q4[1], qC = q4[2], qD = q4[3];
    float d0 = 0.f, d1 = 0.f, d2 = 0.f, d3 = 0.f, Ct = 0.f;
#define CH2(wrd, c0) { \
    float ql = bf2f((u16)((wrd) & 0xffffu)), qh = bf2f((u16)((wrd) >> 16)); \
    float qn0 = sQ[c0] * ql + tQ[c0]; \
    float qn1 = sQ[(c0)+1] * qh + tQ[(c0)+1]; \
    Ct += qn0 * tK[c0] + qn1 * tK[(c0)+1]; \
    float w0 = qn0 * sK[c0], w1 = qn1 * sK[(c0)+1]; \
    d0 += w0 * bf2f(K0[(c0)*HW]) + w1 * bf2f(K0[((c0)+1)*HW]); \
    d1 += w0 * bf2f(K1[(c0)*HW]) + w1 * bf2f(K1[((c0)+1)*HW]); \
    d2 += w0 * bf2f(K2[(c0)*HW]) + w1 * bf2f(K2[((c0)+1)*HW]); \
    d3 += w0 * bf2f(K3[(c0)*HW]) + w1 * bf2f(K3[((c0)+1)*HW]); \
  }
    CH2(qA.x, 0)  CH2(qA.y, 2)  CH2(qA.z, 4)  CH2(qA.w, 6)
    CH2(qB.x, 8)  CH2(qB.y, 10) CH2(qB.z, 12) CH2(qB.w, 14)
    CH2(qC.x, 16) CH2(qC.y, 18) CH2(qC.z, 20) CH2(qC.w, 22)
    CH2(qD.x, 24) CH2(qD.y, 26) CH2(qD.z, 28) CH2(qD.w, 30)
#undef CH2
    const float rs = 0.17677669529663687f;     // 1/sqrt(32)
    float l0 = i0 ? (d0 + Ct) * rs : 0.f;
    float l1 = i1 ? (d1 + Ct) * rs : 0.f;
    float l2 = i2 ? (d2 + Ct) * rs : 0.f;
    float l3 = i3 ? (d3 + Ct) * rs : 0.f;
    float mx = fmaxf(fmaxf(l0, l1), fmaxf(l2, l3));
    float e0 = __expf(l0 - mx), e1 = __expf(l1 - mx);
    float e2 = __expf(l2 - mx), e3 = __expf(l3 - mx);
    float inv = 1.f / (e0 + e1 + e2 + e3);
    a0 = i0 ? e0 * inv : 0.f;  a1 = i1 ? e1 * inv : 0.f;
    a2 = i2 ? e2 * inv : 0.f;  a3 = i3 ? e3 * inv : 0.f;
  }
  __syncthreads();
  // stage V over the same buffer (transposed)
  {
    const uint4* gv = (const uint4*)(qV + (size_t)bh * 11552);
    for (int i = tid; i < 1444; i += 384) {
      uint4 vv = gv[i];
      int pxs = i >> 2, c0 = (i & 3) << 3;
      u16* d = KV + c0 * HW + pxs;
      d[0 * HW] = (u16)(vv.x & 0xffffu); d[1 * HW] = (u16)(vv.x >> 16);
      d[2 * HW] = (u16)(vv.y & 0xffffu); d[3 * HW] = (u16)(vv.y >> 16);
      d[4 * HW] = (u16)(vv.z & 0xffffu); d[5 * HW] = (u16)(vv.z >> 16);
      d[6 * HW] = (u16)(vv.w & 0xffffu); d[7 * HW] = (u16)(vv.w >> 16);
    }
  }
  __syncthreads();

  if (act) {
    const float ai = a0 + a1 + a2 + a3;
    const u16* V0 = KV + pn0; const u16* V1 = KV + pn1;
    const u16* V2 = KV + pn2; const u16* V3 = KV + pn3;
    const size_t gb = ((size_t)bb * 256 + h * 32) * HW + px;
    #pragma unroll
    for (int oc = 0; oc < 32; ++oc) {
      float v = a0 * bf2f(V0[oc * HW]) + a1 * bf2f(V1[oc * HW])
              + a2 * bf2f(V2[oc * HW]) + a3 * bf2f(V3[oc * HW]);
      float o = sV[oc] * v + tV[oc] * ai;
      o = fmaxf(o, 0.f);
      const size_t g = gb + (size_t)oc * HW;
      out[g] = o + x[g];
    }
  }
}

// ---------------- workspace layout
constexpr size_t OFF_XT    = 0;
constexpr size_t SZ_XT     = (size_t)NPIX * 512;
constexpr size_t OFF_WALL  = OFF_XT + SZ_XT;
constexpr size_t SZ_WALL   = (size_t)NTOT * 512;
constexpr size_t OFF_BALL  = OFF_WALL + SZ_WALL;
constexpr size_t OFF_STATS = OFF_BALL + NTOT * 4;
constexpr size_t OFF_SALL  = OFF_STATS + 2 * NTOT * 4;
constexpr size_t OFF_TALL  = OFF_SALL + NTOT * 4;
constexpr size_t OFF_QQ    = OFF_TALL + NTOT * 4;
constexpr size_t SZ_ONE    = (size_t)NPIX * 256 * 2;
constexpr size_t OFF_QK    = OFF_QQ + SZ_ONE;
constexpr size_t OFF_QV    = OFF_QK + SZ_ONE;
constexpr size_t WS_NEEDED = OFF_QV + SZ_ONE;

extern "C" void kernel_launch(void* const* d_in, const int* in_sizes, int n_in,
                              void* d_out, int out_size, void* d_ws, size_t ws_size,
                              hipStream_t stream) {
  (void)in_sizes; (void)n_in; (void)out_size;
  if (ws_size < WS_NEEDED) return;

  const float* x     = (const float*)d_in[0];
  const float* Wq    = (const float*)d_in[1];
  const float* bq    = (const float*)d_in[2];
  const float* Wk    = (const float*)d_in[3];
  const float* bk    = (const float*)d_in[4];
  const float* Wv    = (const float*)d_in[5];
  const float* bv    = (const float*)d_in[6];
  const float* gQ    = (const float*)d_in[7];
  const float* betaQ = (const float*)d_in[8];
  const float* gK    = (const float*)d_in[9];
  const float* betaK = (const float*)d_in[10];
  const float* gV    = (const float*)d_in[11];
  const float* betaV = (const float*)d_in[12];
  float* out = (float*)d_out;

  char* w = (char*)d_ws;
  u16*   xT    = (u16*)(w + OFF_XT);
  u16*   Wall  = (u16*)(w + OFF_WALL);
  float* ball  = (float*)(w + OFF_BALL);
  float* stats = (float*)(w + OFF_STATS);
  float* s_all = (float*)(w + OFF_SALL);
  float* t_all = (float*)(w + OFF_TALL);
  u16*   qQ    = (u16*)(w + OFF_QQ);
  u16*   qK    = (u16*)(w + OFF_QK);
  u16*   qV    = (u16*)(w + OFF_QV);

  k_prep<<<NTOT, 256, 0, stream>>>(Wq, bq, Wk, bk, Wv, bv, Wall, ball, stats);
  k_xt<<<NB, 384, 0, stream>>>(x, xT);
  k_gemm<<<dim3(6, NB), 256, 0, stream>>>(xT, Wall, ball, qQ, qK, qV, stats);
  k_stats<<<1, NTOT, 0, stream>>>(stats, gQ, betaQ, gK, betaK, gV, betaV, s_all, t_all);
  k_attn<<<dim3(NB, NHEADS), 384, 0, stream>>>(qQ, qK, qV, s_all, t_all, x, out);
}

// Round 8
// 416.524 us; speedup vs baseline: 1.4043x; 1.4043x over previous
//
#include <hip/hip_runtime.h>

typedef unsigned short u16;
typedef unsigned int   u32;

#define NB     512
#define INC    256
#define NHEADS 8
#define HW     361
#define NPIX   184832      /* NB*HW */
#define NTOT   768
#define EPSBN  1e-5f

typedef __bf16 bf16x8 __attribute__((ext_vector_type(8)));
typedef float  f32x4  __attribute__((ext_vector_type(4)));

__device__ __forceinline__ u16 f2bf(float f) {
  u32 u = __float_as_uint(f);
  u += 0x7fffu + ((u >> 16) & 1u);          // round-to-nearest-even
  return (u16)(u >> 16);
}
__device__ __forceinline__ float bf2f(u16 v) {
  return __uint_as_float(((u32)v) << 16);
}
__device__ __forceinline__ bf16x8 ldb8(const void* p) {
  return __builtin_bit_cast(bf16x8, *(const uint4*)p);
}

// ---------------- kernel 0: W -> bf16 [768][256] plain rows, bias, zero stats
__global__ __launch_bounds__(256) void k_prep(
    const float* __restrict__ Wq, const float* __restrict__ bq,
    const float* __restrict__ Wk, const float* __restrict__ bk,
    const float* __restrict__ Wv, const float* __restrict__ bv,
    u16* __restrict__ Wall, float* __restrict__ ball, float* __restrict__ stats) {
  const int n = blockIdx.x, t = threadIdx.x;
  const float* src; const float* bs; int r;
  if (n < 256)      { src = Wq; bs = bq; r = n; }
  else if (n < 512) { src = Wk; bs = bk; r = n - 256; }
  else              { src = Wv; bs = bv; r = n - 512; }
  Wall[n * 256 + t] = f2bf(src[r * 256 + t]);
  if (t == 0) ball[n] = bs[r];
  if (n == 0) { for (int i = t; i < 1536; i += 256) stats[i] = 0.f; }
}

// ---------------- kernel 1: fused transpose + QKV GEMM, M-tile 64, 8 waves
// stages x [B][C][HW] f32 -> LDS [64 px][256c bf16, rotated]; wave w = head w;
// outputs [bh][px][32c]; lanes carry channels -> contiguous stores
__global__ __launch_bounds__(512) void k_gemm(
    const float* __restrict__ x, const u16* __restrict__ Wall,
    const float* __restrict__ ball,
    u16* __restrict__ qQ, u16* __restrict__ qK, u16* __restrict__ qV,
    float* __restrict__ stats) {
  __shared__ u16   Al[64 * 256];                   // 32 KB, rotated rows
  __shared__ float bl[NTOT];
  const int tid = threadIdx.x;
  const int tx  = blockIdx.x;                      // 0..5 tile-in-image
  const int bb  = blockIdx.y;
  const int px0 = tx * 64;
  const int nvalid = (px0 + 64 <= HW) ? 64 : (HW - px0);   // 64 or 41

  // ---- staged transpose: x f32 [c][hw] -> Al bf16 [px][c] (rotated granules)
  {
    const int pxl = tid & 63;                      // row in tile
    const int q   = tid >> 6;                      // 0..7, channel quarter-of-8
    int pxr = px0 + pxl; if (pxr >= HW) pxr = HW - 1;   // clamp tail (masked later)
    const float* xp = x + (size_t)bb * INC * HW + pxr;
    char* rowp = (char*)Al + pxl * 512;
    const int rot = (pxl & 7) * 4;
    #pragma unroll
    for (int g4 = 0; g4 < 4; ++g4) {
      const int gg = q * 4 + g4;                   // granule 0..31 (8 ch each)
      const int c0 = gg * 8;
      u32 pk[4];
      #pragma unroll
      for (int j = 0; j < 4; ++j) {
        float lo = xp[(size_t)(c0 + 2 * j) * HW];
        float hi = xp[(size_t)(c0 + 2 * j + 1) * HW];
        pk[j] = (u32)f2bf(lo) | ((u32)f2bf(hi) << 16);
      }
      const int slot = (gg + rot) & 31;
      *(uint4*)(rowp + slot * 16) = make_uint4(pk[0], pk[1], pk[2], pk[3]);
    }
  }
  for (int i = tid; i < NTOT; i += 512) bl[i] = ball[i];
  __syncthreads();

  const int lane = tid & 63, w = tid >> 6;         // 8 waves = 8 heads
  const int l15 = lane & 15, kq = lane >> 4;
  const int col0 = ((kq * 16) + ((l15 & 7) * 64)) & 511;
  const char* Alb = (const char*)Al;
  const size_t obh = ((size_t)bb * NHEADS + w) * (32 * HW);

  // W base for this wave's head; nt stride = 256 rows * 512 B
  const char* wr0 = (const char*)Wall + (size_t)(w * 32 + l15) * 512 + kq * 16;
  bf16x8 pb0 = ldb8(wr0);                          // prefetch nt=0, ks=0
  bf16x8 pb1 = ldb8(wr0 + 8192);

  #pragma unroll 1
  for (int nt = 0; nt < 3; ++nt) {
    f32x4 acc[4][2];
    #pragma unroll
    for (int i = 0; i < 4; ++i) {
      acc[i][0] = (f32x4){0.f,0.f,0.f,0.f};
      acc[i][1] = (f32x4){0.f,0.f,0.f,0.f};
    }
    const char* wrn = wr0 + (size_t)nt * 131072;
    bf16x8 b0 = pb0, b1 = pb1;
    int col = col0;
    #pragma unroll
    for (int ks = 0; ks < 8; ++ks) {
      bf16x8 a[4];
      #pragma unroll
      for (int mi = 0; mi < 4; ++mi)
        a[mi] = ldb8(Alb + (mi * 16 + l15) * 512 + col);
      col = (col + 64) & 511;
      #pragma unroll
      for (int mi = 0; mi < 4; ++mi) {
        acc[mi][0] = __builtin_amdgcn_mfma_f32_16x16x32_bf16(a[mi], b0, acc[mi][0], 0, 0, 0);
        acc[mi][1] = __builtin_amdgcn_mfma_f32_16x16x32_bf16(a[mi], b1, acc[mi][1], 0, 0, 0);
      }
      if (ks < 7) {
        b0 = ldb8(wrn + (ks + 1) * 64);
        b1 = ldb8(wrn + 8192 + (ks + 1) * 64);
      }
    }
    if (nt < 2) {                                  // prefetch next phase ks=0
      pb0 = ldb8(wrn + 131072);
      pb1 = ldb8(wrn + 131072 + 8192);
    }

    u16* qp = (nt == 0) ? qQ : (nt == 1) ? qK : qV;
    #pragma unroll
    for (int ni = 0; ni < 2; ++ni) {
      const int c = ni * 16 + l15;                 // 0..31 within head
      const int n = nt * 256 + w * 32 + c;
      const float bias = bl[n];
      float s = 0.f, q = 0.f;
      #pragma unroll
      for (int mi = 0; mi < 4; ++mi) {
        #pragma unroll
        for (int j = 0; j < 4; ++j) {
          const int pxr = mi * 16 + kq * 4 + j;    // row in tile
          if (pxr < nvalid) {
            float v = acc[mi][ni][j] + bias;
            qp[obh + (size_t)(px0 + pxr) * 32 + c] = f2bf(v);
            s += v; q += v * v;
          }
        }
      }
      s += __shfl_down(s, 32);  q += __shfl_down(q, 32);
      s += __shfl_down(s, 16);  q += __shfl_down(q, 16);
      if (kq == 0) {
        atomicAdd(&stats[n], s);
        atomicAdd(&stats[NTOT + n], q);
      }
    }
  }
}

// ---------------- kernel 2: finalize BN -> s_all, t_all
__global__ void k_stats(const float* __restrict__ stats,
                        const float* __restrict__ gQ, const float* __restrict__ betaQ,
                        const float* __restrict__ gK, const float* __restrict__ betaK,
                        const float* __restrict__ gV, const float* __restrict__ betaV,
                        float* __restrict__ s_all, float* __restrict__ t_all) {
  const int n = threadIdx.x;
  if (n >= NTOT) return;
  const float invP = 1.f / (float)NPIX;
  float mean = stats[n] * invP;
  float var  = stats[NTOT + n] * invP - mean * mean;
  float g, be;
  if (n < 256)      { g = gQ[n];       be = betaQ[n]; }
  else if (n < 512) { g = gK[n - 256]; be = betaK[n - 256]; }
  else              { g = gV[n - 512]; be = betaV[n - 512]; }
  float s = g * rsqrtf(var + EPSBN);
  s_all[n] = s;
  t_all[n] = be - s * mean;
}

// ---------------- kernel 3: neighbor attention + softmax + ReLU + residual
// one block per (bb,h); K then V phase-share one 23KB LDS buffer (transposed on stage)
__global__ __launch_bounds__(384, 6) void k_attn(
    const u16* __restrict__ qQ, const u16* __restrict__ qK, const u16* __restrict__ qV,
    const float* __restrict__ s_all, const float* __restrict__ t_all,
    const float* __restrict__ x, float* __restrict__ out) {
  __shared__ __align__(16) u16 KV[32 * HW];          // [c][px]
  __shared__ float sQ[32], tQ[32], sK[32], tK[32], sV[32], tV[32];
  const int bb = blockIdx.x, h = blockIdx.y, tid = threadIdx.x;
  const int bh = bb * NHEADS + h;

  if (tid < 96) {
    int which = tid >> 5, c = tid & 31;
    float sv = s_all[which * 256 + h * 32 + c];
    float tv = t_all[which * 256 + h * 32 + c];
    if (which == 0)      { sQ[c] = sv; tQ[c] = tv; }
    else if (which == 1) { sK[c] = sv; tK[c] = tv; }
    else                 { sV[c] = sv; tV[c] = tv; }
  }
  // stage K: contiguous read [px][c], transpose into LDS [c][px]
  {
    const uint4* gk = (const uint4*)(qK + (size_t)bh * 11552);
    for (int i = tid; i < 1444; i += 384) {
      uint4 kk = gk[i];
      int px = i >> 2, c0 = (i & 3) << 3;
      u16* d = KV + c0 * HW + px;
      d[0 * HW] = (u16)(kk.x & 0xffffu); d[1 * HW] = (u16)(kk.x >> 16);
      d[2 * HW] = (u16)(kk.y & 0xffffu); d[3 * HW] = (u16)(kk.y >> 16);
      d[4 * HW] = (u16)(kk.z & 0xffffu); d[5 * HW] = (u16)(kk.z >> 16);
      d[6 * HW] = (u16)(kk.w & 0xffffu); d[7 * HW] = (u16)(kk.w >> 16);
    }
  }
  __syncthreads();

  const int px = tid;
  const bool act = tid < HW;
  float a0 = 0.f, a1 = 0.f, a2 = 0.f, a3 = 0.f;
  int pn0 = 0, pn1 = 0, pn2 = 0, pn3 = 0;
  if (act) {
    const int yy = px / 19, xx = px - yy * 19;
    const bool i0 = yy > 0, i1 = yy < 18, i2 = xx > 0, i3 = xx < 18;
    pn0 = i0 ? px - 19 : px;  pn1 = i1 ? px + 19 : px;
    pn2 = i2 ? px - 1  : px;  pn3 = i3 ? px + 1  : px;
    const u16* K0 = KV + pn0; const u16* K1 = KV + pn1;
    const u16* K2 = KV + pn2; const u16* K3 = KV + pn3;
    const uint4* q4 = (const uint4*)(qQ + ((size_t)bh * HW + px) * 32);
    uint4 qA = q4[0], qB = q4[1], qC = q4[2], qD = q4[3];
    float d0 = 0.f, d1 = 0.f, d2 = 0.f, d3 = 0.f, Ct = 0.f;
#define CH2(wrd, c0) { \
    float ql = bf2f((u16)((wrd) & 0xffffu)), qh = bf2f((u16)((wrd) >> 16)); \
    float qn0 = sQ[c0] * ql + tQ[c0]; \
    float qn1 = sQ[(c0)+1] * qh + tQ[(c0)+1]; \
    Ct += qn0 * tK[c0] + qn1 * tK[(c0)+1]; \
    float w0 = qn0 * sK[c0], w1 = qn1 * sK[(c0)+1]; \
    d0 += w0 * bf2f(K0[(c0)*HW]) + w1 * bf2f(K0[((c0)+1)*HW]); \
    d1 += w0 * bf2f(K1[(c0)*HW]) + w1 * bf2f(K1[((c0)+1)*HW]); \
    d2 += w0 * bf2f(K2[(c0)*HW]) + w1 * bf2f(K2[((c0)+1)*HW]); \
    d3 += w0 * bf2f(K3[(c0)*HW]) + w1 * bf2f(K3[((c0)+1)*HW]); \
  }
    CH2(qA.x, 0)  CH2(qA.y, 2)  CH2(qA.z, 4)  CH2(qA.w, 6)
    CH2(qB.x, 8)  CH2(qB.y, 10) CH2(qB.z, 12) CH2(qB.w, 14)
    CH2(qC.x, 16) CH2(qC.y, 18) CH2(qC.z, 20) CH2(qC.w, 22)
    CH2(qD.x, 24) CH2(qD.y, 26) CH2(qD.z, 28) CH2(qD.w, 30)
#undef CH2
    const float rs = 0.17677669529663687f;     // 1/sqrt(32)
    float l0 = i0 ? (d0 + Ct) * rs : 0.f;
    float l1 = i1 ? (d1 + Ct) * rs : 0.f;
    float l2 = i2 ? (d2 + Ct) * rs : 0.f;
    float l3 = i3 ? (d3 + Ct) * rs : 0.f;
    float mx = fmaxf(fmaxf(l0, l1), fmaxf(l2, l3));
    float e0 = __expf(l0 - mx), e1 = __expf(l1 - mx);
    float e2 = __expf(l2 - mx), e3 = __expf(l3 - mx);
    float inv = 1.f / (e0 + e1 + e2 + e3);
    a0 = i0 ? e0 * inv : 0.f;  a1 = i1 ? e1 * inv : 0.f;
    a2 = i2 ? e2 * inv : 0.f;  a3 = i3 ? e3 * inv : 0.f;
  }
  __syncthreads();
  // stage V over the same buffer (transposed)
  {
    const uint4* gv = (const uint4*)(qV + (size_t)bh * 11552);
    for (int i = tid; i < 1444; i += 384) {
      uint4 vv = gv[i];
      int pxs = i >> 2, c0 = (i & 3) << 3;
      u16* d = KV + c0 * HW + pxs;
      d[0 * HW] = (u16)(vv.x & 0xffffu); d[1 * HW] = (u16)(vv.x >> 16);
      d[2 * HW] = (u16)(vv.y & 0xffffu); d[3 * HW] = (u16)(vv.y >> 16);
      d[4 * HW] = (u16)(vv.z & 0xffffu); d[5 * HW] = (u16)(vv.z >> 16);
      d[6 * HW] = (u16)(vv.w & 0xffffu); d[7 * HW] = (u16)(vv.w >> 16);
    }
  }
  __syncthreads();

  if (act) {
    const float ai = a0 + a1 + a2 + a3;
    const u16* V0 = KV + pn0; const u16* V1 = KV + pn1;
    const u16* V2 = KV + pn2; const u16* V3 = KV + pn3;
    const size_t gb = ((size_t)bb * 256 + h * 32) * HW + px;
    #pragma unroll
    for (int oc = 0; oc < 32; ++oc) {
      float v = a0 * bf2f(V0[oc * HW]) + a1 * bf2f(V1[oc * HW])
              + a2 * bf2f(V2[oc * HW]) + a3 * bf2f(V3[oc * HW]);
      float o = sV[oc] * v + tV[oc] * ai;
      o = fmaxf(o, 0.f);
      const size_t g = gb + (size_t)oc * HW;
      out[g] = o + x[g];
    }
  }
}

// ---------------- workspace layout (xT removed)
constexpr size_t OFF_WALL  = 0;
constexpr size_t SZ_WALL   = (size_t)NTOT * 512;
constexpr size_t OFF_BALL  = OFF_WALL + SZ_WALL;
constexpr size_t OFF_STATS = OFF_BALL + NTOT * 4;
constexpr size_t OFF_SALL  = OFF_STATS + 2 * NTOT * 4;
constexpr size_t OFF_TALL  = OFF_SALL + NTOT * 4;
constexpr size_t OFF_QQ    = OFF_TALL + NTOT * 4;
constexpr size_t SZ_ONE    = (size_t)NPIX * 256 * 2;
constexpr size_t OFF_QK    = OFF_QQ + SZ_ONE;
constexpr size_t OFF_QV    = OFF_QK + SZ_ONE;
constexpr size_t WS_NEEDED = OFF_QV + SZ_ONE;

extern "C" void kernel_launch(void* const* d_in, const int* in_sizes, int n_in,
                              void* d_out, int out_size, void* d_ws, size_t ws_size,
                              hipStream_t stream) {
  (void)in_sizes; (void)n_in; (void)out_size;
  if (ws_size < WS_NEEDED) return;

  const float* x     = (const float*)d_in[0];
  const float* Wq    = (const float*)d_in[1];
  const float* bq    = (const float*)d_in[2];
  const float* Wk    = (const float*)d_in[3];
  const float* bk    = (const float*)d_in[4];
  const float* Wv    = (const float*)d_in[5];
  const float* bv    = (const float*)d_in[6];
  const float* gQ    = (const float*)d_in[7];
  const float* betaQ = (const float*)d_in[8];
  const float* gK    = (const float*)d_in[9];
  const float* betaK = (const float*)d_in[10];
  const float* gV    = (const float*)d_in[11];
  const float* betaV = (const float*)d_in[12];
  float* out = (float*)d_out;

  char* wsp = (char*)d_ws;
  u16*   Wall  = (u16*)(wsp + OFF_WALL);
  float* ball  = (float*)(wsp + OFF_BALL);
  float* stats = (float*)(wsp + OFF_STATS);
  float* s_all = (float*)(wsp + OFF_SALL);
  float* t_all = (float*)(wsp + OFF_TALL);
  u16*   qQ    = (u16*)(wsp + OFF_QQ);
  u16*   qK    = (u16*)(wsp + OFF_QK);
  u16*   qV    = (u16*)(wsp + OFF_QV);

  k_prep<<<NTOT, 256, 0, stream>>>(Wq, bq, Wk, bk, Wv, bv, Wall, ball, stats);
  k_gemm<<<dim3(6, NB), 512, 0, stream>>>(x, Wall, ball, qQ, qK, qV, stats);
  k_stats<<<1, NTOT, 0, stream>>>(stats, gQ, betaQ, gK, betaK, gV, betaV, s_all, t_all);
  k_attn<<<dim3(NB, NHEADS), 384, 0, stream>>>(qQ, qK, qV, s_all, t_all, x, out);
}